// Round 4
// baseline (808.003 us; speedup 1.0000x reference)
//
#include <hip/hip_runtime.h>
#include <hip/hip_bf16.h>

// Problem constants (fixed by setup_inputs in the reference)
#define B_    16
#define N_    1536
#define C_    768
#define N0_   3072
#define H_    64
#define W_    48
#define HW_   (H_ * W_)        // 3072
#define NPTS  (B_ * N0_)       // 49152
#define NTOK  (B_ * N_)        // 24576
#define EPS_  1e-6f

static __device__ __forceinline__ float bf2f(__hip_bfloat16 v) {
    return __bfloat162float(v);
}
// dtype-flexible load: isf=1 -> buffer holds float32, else bf16
static __device__ __forceinline__ float loadf(const void* p, size_t i, int isf) {
    return isf ? ((const float*)p)[i] : bf2f(((const __hip_bfloat16*)p)[i]);
}

// ---------------- dtype probe on agg_weight (values in [0,1)) ----------------
// bf16 storage: every uint16 slot has sign=0 and value <= 0x3F80 (1.0) -> 0 bad.
// fp32 storage: even slots are random fp32 low-mantissa bits -> ~75% bad.
__global__ void k_probe(const unsigned short* __restrict__ aw, int* __restrict__ flag) {
    __shared__ int cnt;
    if (threadIdx.x == 0) cnt = 0;
    __syncthreads();
    unsigned short v = aw[threadIdx.x];   // 128 slots = 256 B, safe for either dtype
    int bad = ((v & 0x8000u) != 0) || (v > 0x3F80u);
    if (bad) atomicAdd(&cnt, 1);
    __syncthreads();
    if (threadIdx.x == 0) *flag = (cnt >= 4) ? 1 : 0;
}

// ---------------- conv weight/bias -> f32 ----------------
__global__ void k_convert(const void* __restrict__ conv_w,
                          const void* __restrict__ conv_b,
                          const int* __restrict__ flag,
                          float* __restrict__ kw, float* __restrict__ cb) {
    int isf = *flag;
    int i = blockIdx.x * blockDim.x + threadIdx.x;
    if (i < C_ * 9) kw[i] = loadf(conv_w, i, isf);
    else if (i < C_ * 9 + C_) cb[i - C_ * 9] = loadf(conv_b, i - C_ * 9, isf);
}

// ---------------- per-point precompute + histogram ----------------
__global__ void k_points(const void* __restrict__ loc_orig,
                         const int* __restrict__ idx_agg,
                         const void* __restrict__ agg_w,
                         const int* __restrict__ flag,
                         int* __restrict__ pixkey, uchar4* __restrict__ quad,
                         float* __restrict__ wxa, float* __restrict__ wya,
                         float* __restrict__ wa,
                         int* __restrict__ cnt_pix, int* __restrict__ cnt_tok) {
    int i = blockIdx.x * blockDim.x + threadIdx.x;
    if (i >= NPTS) return;
    int isf = *flag;
    int b = i / N0_;
    float lx = loadf(loc_orig, 2 * (size_t)i, isf);
    float ly = loadf(loc_orig, 2 * (size_t)i + 1, isf);
    lx = fminf(fmaxf(lx, -1.f), 1.f);
    ly = fminf(fmaxf(ly, -1.f), 1.f);
    // pos = 0.5*(l+1)*wh - 0.5  (exact f32, matches np ref)
    float px = 0.5f * (lx + 1.f) * (float)W_ - 0.5f;
    float py = 0.5f * (ly + 1.f) * (float)H_ - 0.5f;
    // nearest pixel (round-half-even == np.round)
    int ixn = min(max((int)rintf(px), 0), W_ - 1);
    int iyn = min(max((int)rintf(py), 0), H_ - 1);
    int pk = b * HW_ + iyn * W_ + ixn;
    pixkey[i] = pk;
    // bilinear corners (clipped), weights per reference (may be negative at edges)
    int x0 = min(max((int)floorf(px), 0), W_ - 1);
    int x1 = min(x0 + 1, W_ - 1);
    int y0 = min(max((int)floorf(py), 0), H_ - 1);
    int y1 = min(y0 + 1, H_ - 1);
    wxa[i] = fminf((float)x1, px) - (float)x0;
    wya[i] = fminf((float)y1, py) - (float)y0;
    quad[i] = make_uchar4((unsigned char)x0, (unsigned char)y0,
                          (unsigned char)x1, (unsigned char)y1);
    wa[i] = loadf(agg_w, i, isf);
    atomicAdd(&cnt_pix[pk], 1);
    atomicAdd(&cnt_tok[b * N_ + idx_agg[i]], 1);
}

// ---------------- single-block exclusive scan (n <= 49152) ----------------
__global__ void k_scan(const int* __restrict__ cnt, int n,
                       int* __restrict__ off, int* __restrict__ cur) {
    __shared__ int sh[1024];
    int t = threadIdx.x;
    int per = (n + 1023) >> 10;
    int start = t * per;
    int s = 0;
    for (int i = 0; i < per; ++i) {
        int idx = start + i;
        if (idx < n) s += cnt[idx];
    }
    sh[t] = s;
    __syncthreads();
    for (int d = 1; d < 1024; d <<= 1) {
        int v = sh[t];
        int add = (t >= d) ? sh[t - d] : 0;
        __syncthreads();
        sh[t] = v + add;
        __syncthreads();
    }
    int run = (t == 0) ? 0 : sh[t - 1];
    for (int i = 0; i < per; ++i) {
        int idx = start + i;
        if (idx < n) {
            off[idx] = run;
            cur[idx] = run;
            run += cnt[idx];
        }
    }
    if (t == 1023) off[n] = sh[1023];
}

// ---------------- CSR fill ----------------
__global__ void k_fill(const int* __restrict__ pixkey, const int* __restrict__ idx_agg,
                       int* __restrict__ cur_pix, int* __restrict__ cur_tok,
                       int* __restrict__ list_pix, int* __restrict__ list_tok) {
    int i = blockIdx.x * blockDim.x + threadIdx.x;
    if (i >= NPTS) return;
    int b = i / N0_;
    int s1 = atomicAdd(&cur_pix[pixkey[i]], 1);
    list_pix[s1] = i;
    int s2 = atomicAdd(&cur_tok[b * N_ + idx_agg[i]], 1);
    list_tok[s2] = i;
}

// ---------------- token2map: per-pixel gather, normalized write ----------------
__global__ __launch_bounds__(128)
void k_scatter(const void* __restrict__ xv, const int* __restrict__ idx_agg,
               const int* __restrict__ off_pix, const int* __restrict__ list_pix,
               const int* __restrict__ flag,
               float* __restrict__ fmap, int cbase, int cc) {
    int pk = blockIdx.x;          // [0, B*HW)
    int t = threadIdx.x;
    int bd = blockDim.x;
    int b = pk / HW_;
    int s = off_pix[pk], e = off_pix[pk + 1];
    int isf = *flag;
    float acc[3] = {0.f, 0.f, 0.f};
    if (isf) {
        const float* xf = (const float*)xv;
        for (int j = s; j < e; ++j) {
            int tok = idx_agg[list_pix[j]];
            const float* row = xf + ((size_t)(b * N_ + tok)) * C_ + cbase + t;
            int r = 0;
            for (int c = t; c < cc; c += bd, ++r) acc[r] += row[r * bd];
        }
    } else {
        const __hip_bfloat16* xb = (const __hip_bfloat16*)xv;
        for (int j = s; j < e; ++j) {
            int tok = idx_agg[list_pix[j]];
            const __hip_bfloat16* row = xb + ((size_t)(b * N_ + tok)) * C_ + cbase + t;
            int r = 0;
            for (int c = t; c < cc; c += bd, ++r) acc[r] += bf2f(row[r * bd]);
        }
    }
    float sc = 1.f / ((float)(e - s) + EPS_);   // num/(cnt+eps)
    float* dst = fmap + (size_t)pk * cc + t;
    int r = 0;
    for (int c = t; c < cc; c += bd, ++r) dst[r * bd] = acc[r] * sc;
}

// ---------------- depthwise 3x3 conv, channel-last, zero padded ----------------
__global__ __launch_bounds__(384)
void k_conv(const float* __restrict__ fmap, const float* __restrict__ kw,
            const float* __restrict__ cb, float* __restrict__ out, int cbase, int cc) {
    int hw = blockIdx.x;
    int b = blockIdx.y;
    int c = threadIdx.x;          // < cc
    int y = hw / W_;
    int xx = hw - y * W_;
    const float* base = fmap + (size_t)b * HW_ * cc;
    const float* kr = kw + (size_t)(cbase + c) * 9;
    float acc = cb[cbase + c];
#pragma unroll
    for (int ky = 0; ky < 3; ++ky) {
        int yy = y + ky - 1;
        if ((unsigned)yy >= (unsigned)H_) continue;
#pragma unroll
        for (int kx = 0; kx < 3; ++kx) {
            int xw = xx + kx - 1;
            if ((unsigned)xw >= (unsigned)W_) continue;
            acc += kr[ky * 3 + kx] * base[(size_t)(yy * W_ + xw) * cc + c];
        }
    }
    out[(size_t)b * HW_ * cc + (size_t)hw * cc + c] = acc;
}

// ---------------- map2token: per-token gather, bilinear + weighted agg ----------------
// Output write matches detected dtype: fp32 world -> fp32 out, bf16 world -> bf16 out.
__global__ __launch_bounds__(128)
void k_gather(const float* __restrict__ convout,
              const int* __restrict__ off_tok, const int* __restrict__ list_tok,
              const uchar4* __restrict__ quad, const float* __restrict__ wxa,
              const float* __restrict__ wya, const float* __restrict__ wa,
              const int* __restrict__ flag,
              void* __restrict__ outv, int cbase, int cc) {
    int tk = blockIdx.x;          // [0, B*N)
    int t = threadIdx.x;
    int bd = blockDim.x;
    int b = tk / N_;
    int s = off_tok[tk], e = off_tok[tk + 1];
    float wsum = EPS_;
    for (int j = s; j < e; ++j) wsum += wa[list_tok[j]];
    float acc[3] = {0.f, 0.f, 0.f};
    const float* bb = convout + (size_t)b * HW_ * cc;
    for (int j = s; j < e; ++j) {
        int i = list_tok[j];
        float wn = wa[i] / wsum;
        uchar4 q = quad[i];                       // x0,y0,x1,y1
        float wx = wxa[i], wy = wya[i];
        float w00 = (1.f - wx) * (1.f - wy) * wn;
        float w01 = wx * (1.f - wy) * wn;
        float w10 = (1.f - wx) * wy * wn;
        float w11 = wx * wy * wn;
        const float* p00 = bb + (size_t)(q.y * W_ + q.x) * cc + t;
        const float* p01 = bb + (size_t)(q.y * W_ + q.z) * cc + t;
        const float* p10 = bb + (size_t)(q.w * W_ + q.x) * cc + t;
        const float* p11 = bb + (size_t)(q.w * W_ + q.z) * cc + t;
        int r = 0;
        for (int c = t; c < cc; c += bd, ++r) {
            acc[r] += w00 * p00[r * bd] + w01 * p01[r * bd]
                    + w10 * p10[r * bd] + w11 * p11[r * bd];
        }
    }
    if (*flag) {
        float* dst = (float*)outv + (size_t)tk * C_ + cbase + t;
        int r = 0;
        for (int c = t; c < cc; c += bd, ++r) dst[r * bd] = acc[r];
    } else {
        __hip_bfloat16* dst = (__hip_bfloat16*)outv + (size_t)tk * C_ + cbase + t;
        int r = 0;
        for (int c = t; c < cc; c += bd, ++r) dst[r * bd] = __float2bfloat16(acc[r]);
    }
}

extern "C" void kernel_launch(void* const* d_in, const int* in_sizes, int n_in,
                              void* d_out, int out_size, void* d_ws, size_t ws_size,
                              hipStream_t stream) {
    const void* x        = d_in[0];
    // d_in[1] = loc (unused by reference)
    const void* loc_orig = d_in[2];
    const int*  idx_agg  = (const int*)d_in[3];
    const void* agg_w    = d_in[4];
    // d_in[5]=H (64), d_in[6]=W (48) — fixed, hard-coded
    const void* conv_w   = d_in[7];
    const void* conv_b   = d_in[8];

    char* wsp = (char*)d_ws;
    size_t o = 0;
    auto alloc = [&](size_t bytes) -> void* {
        o = (o + 255) & ~(size_t)255;
        void* p = wsp + o;
        o += bytes;
        return p;
    };
    int*    dflag    = (int*)alloc(sizeof(int));
    float*  kw       = (float*)alloc(C_ * 9 * sizeof(float));
    float*  cb       = (float*)alloc(C_ * sizeof(float));
    int*    pixkey   = (int*)alloc(NPTS * sizeof(int));
    uchar4* quad     = (uchar4*)alloc(NPTS * sizeof(uchar4));
    float*  wxa      = (float*)alloc(NPTS * sizeof(float));
    float*  wya      = (float*)alloc(NPTS * sizeof(float));
    float*  wa       = (float*)alloc(NPTS * sizeof(float));
    int*    cnt_pix  = (int*)alloc((size_t)(B_ * HW_ + NTOK) * sizeof(int));
    int*    cnt_tok  = cnt_pix + B_ * HW_;
    int*    off_pix  = (int*)alloc((size_t)(B_ * HW_ + 1) * sizeof(int));
    int*    off_tok  = (int*)alloc((size_t)(NTOK + 1) * sizeof(int));
    int*    cur_pix  = (int*)alloc((size_t)(B_ * HW_) * sizeof(int));
    int*    cur_tok  = (int*)alloc((size_t)NTOK * sizeof(int));
    int*    list_pix = (int*)alloc(NPTS * sizeof(int));
    int*    list_tok = (int*)alloc(NPTS * sizeof(int));

    // ---- adaptive channel chunk so fmap+convout fit in ws_size ----
    size_t small_end = (o + 255) & ~(size_t)255;
    size_t perchan = (size_t)B_ * HW_ * 2 * sizeof(float);   // bytes/channel for BOTH buffers
    size_t avail = (ws_size > small_end + 1024) ? ws_size - small_end - 1024 : 0;
    int cc = 8;   // absolute floor: ~5.5 MB total
    const int ladder[6] = {384, 256, 128, 64, 32, 16};
    for (int k = 0; k < 6; ++k) {
        if (avail >= (size_t)ladder[k] * perchan) { cc = ladder[k]; break; }
    }
    int tpb = (cc >= 128) ? 128 : cc;
    int nchunk = C_ / cc;

    float* fmap    = (float*)alloc((size_t)B_ * HW_ * cc * sizeof(float));
    float* convout = (float*)alloc((size_t)B_ * HW_ * cc * sizeof(float));

    // zero the two count arrays (contiguous)
    hipMemsetAsync(cnt_pix, 0, (size_t)(B_ * HW_ + NTOK) * sizeof(int), stream);

    k_probe<<<1, 128, 0, stream>>>((const unsigned short*)agg_w, dflag);
    k_convert<<<(C_ * 9 + C_ + 255) / 256, 256, 0, stream>>>(conv_w, conv_b, dflag, kw, cb);
    k_points<<<NPTS / 256, 256, 0, stream>>>(loc_orig, idx_agg, agg_w, dflag,
                                             pixkey, quad, wxa, wya, wa,
                                             cnt_pix, cnt_tok);
    k_scan<<<1, 1024, 0, stream>>>(cnt_pix, B_ * HW_, off_pix, cur_pix);
    k_scan<<<1, 1024, 0, stream>>>(cnt_tok, NTOK, off_tok, cur_tok);
    k_fill<<<NPTS / 256, 256, 0, stream>>>(pixkey, idx_agg, cur_pix, cur_tok,
                                           list_pix, list_tok);

    for (int chunk = 0; chunk < nchunk; ++chunk) {
        int cbase = chunk * cc;
        k_scatter<<<B_ * HW_, tpb, 0, stream>>>(x, idx_agg, off_pix, list_pix, dflag,
                                                fmap, cbase, cc);
        dim3 gconv(HW_, B_);
        k_conv<<<gconv, cc, 0, stream>>>(fmap, kw, cb, convout, cbase, cc);
        k_gather<<<NTOK, tpb, 0, stream>>>(convout, off_tok, list_tok,
                                           quad, wxa, wya, wa, dflag, d_out, cbase, cc);
    }
}

// Round 5
// 511.953 us; speedup vs baseline: 1.5783x; 1.5783x over previous
//
#include <hip/hip_runtime.h>

// Problem constants (fixed by setup_inputs in the reference; fp32 world confirmed R4)
#define B_    16
#define N_    1536
#define C_    768
#define N0_   3072
#define H_    64
#define W_    48
#define HW_   (H_ * W_)        // 3072
#define NPTS  (B_ * N0_)       // 49152
#define NTOK  (B_ * N_)        // 24576
#define EPS_  1e-6f
#define TY_   4                // conv tile rows per block
#define TX_   8                // conv tile cols per block

// ---------------- transpose conv weights to [9][C] for coalesced conv reads ----
__global__ void k_wT(const float* __restrict__ w, float* __restrict__ wT) {
    int i = blockIdx.x * blockDim.x + threadIdx.x;   // over C_*9
    if (i < C_ * 9) { int c = i / 9, k = i - c * 9; wT[k * C_ + c] = w[i]; }
}

// ---------------- per-point precompute + histograms + wsum ----------------
__global__ void k_points(const float* __restrict__ loc_orig,
                         const int* __restrict__ idx_agg,
                         const float* __restrict__ agg_w,
                         int* __restrict__ pixkey, int4* __restrict__ ofs4,
                         float* __restrict__ wxa, float* __restrict__ wya,
                         float* __restrict__ wa,
                         int* __restrict__ cnt_pix, int* __restrict__ cnt_tok,
                         float* __restrict__ wsum) {
    int i = blockIdx.x * blockDim.x + threadIdx.x;
    if (i >= NPTS) return;
    int b = i / N0_;
    float lx = loc_orig[2 * (size_t)i];
    float ly = loc_orig[2 * (size_t)i + 1];
    lx = fminf(fmaxf(lx, -1.f), 1.f);
    ly = fminf(fmaxf(ly, -1.f), 1.f);
    float px = 0.5f * (lx + 1.f) * (float)W_ - 0.5f;   // matches np ref exactly
    float py = 0.5f * (ly + 1.f) * (float)H_ - 0.5f;
    // nearest pixel (round-half-even == np.round)
    int ixn = min(max((int)rintf(px), 0), W_ - 1);
    int iyn = min(max((int)rintf(py), 0), H_ - 1);
    int pk = b * HW_ + iyn * W_ + ixn;
    pixkey[i] = pk;
    // bilinear corners (clipped), weights per reference (may be negative at edges)
    int x0 = min(max((int)floorf(px), 0), W_ - 1);
    int x1 = min(x0 + 1, W_ - 1);
    int y0 = min(max((int)floorf(py), 0), H_ - 1);
    int y1 = min(y0 + 1, H_ - 1);
    wxa[i] = fminf((float)x1, px) - (float)x0;
    wya[i] = fminf((float)y1, py) - (float)y0;
    ofs4[i] = make_int4(y0 * W_ + x0, y0 * W_ + x1, y1 * W_ + x0, y1 * W_ + x1);
    float w = agg_w[i];
    wa[i] = w;
    atomicAdd(&cnt_pix[pk], 1);
    int tk = b * N_ + idx_agg[i];
    atomicAdd(&cnt_tok[tk], 1);
    atomicAdd(&wsum[tk], w);
}

// ---------------- single-block exclusive scan (n <= 49152) ----------------
__global__ void k_scan(const int* __restrict__ cnt, int n,
                       int* __restrict__ off, int* __restrict__ cur) {
    __shared__ int sh[1024];
    int t = threadIdx.x;
    int per = (n + 1023) >> 10;
    int start = t * per;
    int s = 0;
    for (int i = 0; i < per; ++i) {
        int idx = start + i;
        if (idx < n) s += cnt[idx];
    }
    sh[t] = s;
    __syncthreads();
    for (int d = 1; d < 1024; d <<= 1) {
        int v = sh[t];
        int add = (t >= d) ? sh[t - d] : 0;
        __syncthreads();
        sh[t] = v + add;
        __syncthreads();
    }
    int run = (t == 0) ? 0 : sh[t - 1];
    for (int i = 0; i < per; ++i) {
        int idx = start + i;
        if (idx < n) {
            off[idx] = run;
            cur[idx] = run;
            run += cnt[idx];
        }
    }
    if (t == 1023) off[n] = sh[1023];
}

// ---------------- CSR fill + precompute premultiplied bilinear weights ----------
__global__ void k_fill(const int* __restrict__ pixkey, const int* __restrict__ idx_agg,
                       const float* __restrict__ wxa, const float* __restrict__ wya,
                       const float* __restrict__ wa, const float* __restrict__ wsum,
                       int* __restrict__ cur_pix, int* __restrict__ cur_tok,
                       int* __restrict__ list_pix, int* __restrict__ list_tok,
                       float4* __restrict__ wts4) {
    int i = blockIdx.x * blockDim.x + threadIdx.x;
    if (i >= NPTS) return;
    int b = i / N0_;
    int tok = idx_agg[i];
    int tk = b * N_ + tok;
    int s1 = atomicAdd(&cur_pix[pixkey[i]], 1);
    list_pix[s1] = tk;                 // direct x-row index for scatter
    int s2 = atomicAdd(&cur_tok[tk], 1);
    list_tok[s2] = i;
    float wn = wa[i] / (wsum[tk] + EPS_);    // ref: w / (segsum + eps)
    float wx = wxa[i], wy = wya[i];
    wts4[i] = make_float4((1.f - wx) * (1.f - wy) * wn, wx * (1.f - wy) * wn,
                          (1.f - wx) * wy * wn,         wx * wy * wn);
}

// ---------------- token2map: per-pixel float4 gather, normalized write --------
template<int CC>
__global__ __launch_bounds__(CC / 4)
void k_scatter(const float4* __restrict__ x4, const int* __restrict__ off_pix,
               const int* __restrict__ list_pix, float4* __restrict__ fmap4,
               int cbase4) {
    int pk = blockIdx.x;              // [0, B*HW)
    int t = threadIdx.x;              // [0, CC/4)
    int s = off_pix[pk], e = off_pix[pk + 1];
    float4 a = make_float4(0.f, 0.f, 0.f, 0.f);
    for (int j = s; j < e; ++j) {
        int row = list_pix[j];        // b*N + tok
        float4 v = x4[(size_t)row * (C_ / 4) + cbase4 + t];
        a.x += v.x; a.y += v.y; a.z += v.z; a.w += v.w;
    }
    float sc = 1.f / ((float)(e - s) + EPS_);
    a.x *= sc; a.y *= sc; a.z *= sc; a.w *= sc;
    fmap4[(size_t)pk * (CC / 4) + t] = a;
}

// ---------------- depthwise 3x3, register-tiled TYxTX pixels per thread -------
template<int CC>
__global__ __launch_bounds__(CC)
void k_conv(const float* __restrict__ fmap, const float* __restrict__ wT,
            const float* __restrict__ cb, float* __restrict__ out, int cbase) {
    int tile = blockIdx.x;                        // (W/TX)*(H/TY) tiles
    int tx0 = (tile % (W_ / TX_)) * TX_;
    int ty0 = (tile / (W_ / TX_)) * TY_;
    int b = blockIdx.y;
    int c = threadIdx.x;                          // < CC
    const float* base = fmap + (size_t)b * HW_ * CC + c;
    float v[TY_ + 2][TX_ + 2];
#pragma unroll
    for (int r = 0; r < TY_ + 2; ++r) {
        int yy = ty0 + r - 1;
        bool yok = (unsigned)yy < (unsigned)H_;
#pragma unroll
        for (int j = 0; j < TX_ + 2; ++j) {
            int xx = tx0 + j - 1;
            bool ok = yok && ((unsigned)xx < (unsigned)W_);   // block-uniform predicate
            v[r][j] = ok ? base[(size_t)(yy * W_ + xx) * CC] : 0.f;
        }
    }
    int cg = cbase + c;
    float k0 = wT[0 * C_ + cg], k1 = wT[1 * C_ + cg], k2 = wT[2 * C_ + cg];
    float k3 = wT[3 * C_ + cg], k4 = wT[4 * C_ + cg], k5 = wT[5 * C_ + cg];
    float k6 = wT[6 * C_ + cg], k7 = wT[7 * C_ + cg], k8 = wT[8 * C_ + cg];
    float bias = cb[cg];
    float* ob = out + (size_t)b * HW_ * CC + c;
#pragma unroll
    for (int r = 0; r < TY_; ++r) {
#pragma unroll
        for (int j = 0; j < TX_; ++j) {
            float acc = bias
                + k0 * v[r][j]     + k1 * v[r][j + 1]     + k2 * v[r][j + 2]
                + k3 * v[r + 1][j] + k4 * v[r + 1][j + 1] + k5 * v[r + 1][j + 2]
                + k6 * v[r + 2][j] + k7 * v[r + 2][j + 1] + k8 * v[r + 2][j + 2];
            ob[(size_t)((ty0 + r) * W_ + tx0 + j) * CC] = acc;
        }
    }
}

// ---------------- map2token: per-token float4 gather with precomputed wts -----
template<int CC>
__global__ __launch_bounds__(CC / 4)
void k_gather(const float4* __restrict__ conv4, const int* __restrict__ off_tok,
              const int* __restrict__ list_tok, const int4* __restrict__ ofs4,
              const float4* __restrict__ wts4, float4* __restrict__ out4,
              int cbase4) {
    int tk = blockIdx.x;              // [0, B*N)
    int t = threadIdx.x;              // [0, CC/4)
    int b = tk / N_;
    int s = off_tok[tk], e = off_tok[tk + 1];
    const float4* bb = conv4 + (size_t)b * HW_ * (CC / 4) + t;
    float4 a = make_float4(0.f, 0.f, 0.f, 0.f);
    for (int j = s; j < e; ++j) {
        int i = list_tok[j];
        int4 o = ofs4[i];             // uniform 16B load
        float4 w = wts4[i];           // uniform 16B load (already *wn)
        float4 p0 = bb[(size_t)o.x * (CC / 4)];
        float4 p1 = bb[(size_t)o.y * (CC / 4)];
        float4 p2 = bb[(size_t)o.z * (CC / 4)];
        float4 p3 = bb[(size_t)o.w * (CC / 4)];
        a.x += w.x * p0.x + w.y * p1.x + w.z * p2.x + w.w * p3.x;
        a.y += w.x * p0.y + w.y * p1.y + w.z * p2.y + w.w * p3.y;
        a.z += w.x * p0.z + w.y * p1.z + w.z * p2.z + w.w * p3.z;
        a.w += w.x * p0.w + w.y * p1.w + w.z * p2.w + w.w * p3.w;
    }
    out4[(size_t)tk * (C_ / 4) + cbase4 + t] = a;
}

// ---------------- templated chunk-loop driver ----------------
template<int CC>
static void run_chunks(const float4* x4, const int* off_pix, const int* list_pix,
                       const int* off_tok, const int* list_tok,
                       const int4* ofs4, const float4* wts4,
                       const float* wT, const float* cb,
                       float* fmap, float* convout, float* out,
                       hipStream_t stream) {
    constexpr int NCH = C_ / CC;
    for (int chunk = 0; chunk < NCH; ++chunk) {
        int cbase = chunk * CC;
        k_scatter<CC><<<B_ * HW_, CC / 4, 0, stream>>>(
            x4, off_pix, list_pix, (float4*)fmap, cbase / 4);
        dim3 gconv((W_ / TX_) * (H_ / TY_), B_);
        k_conv<CC><<<gconv, CC, 0, stream>>>(fmap, wT, cb, convout, cbase);
        k_gather<CC><<<NTOK, CC / 4, 0, stream>>>(
            (const float4*)convout, off_tok, list_tok, ofs4, wts4,
            (float4*)out, cbase / 4);
    }
}

extern "C" void kernel_launch(void* const* d_in, const int* in_sizes, int n_in,
                              void* d_out, int out_size, void* d_ws, size_t ws_size,
                              hipStream_t stream) {
    const float* x        = (const float*)d_in[0];
    // d_in[1] = loc (unused by reference)
    const float* loc_orig = (const float*)d_in[2];
    const int*   idx_agg  = (const int*)d_in[3];
    const float* agg_w    = (const float*)d_in[4];
    // d_in[5]=H (64), d_in[6]=W (48) fixed
    const float* conv_w   = (const float*)d_in[7];
    const float* conv_b   = (const float*)d_in[8];
    float* out = (float*)d_out;

    char* wsp = (char*)d_ws;
    size_t o = 0;
    auto alloc = [&](size_t bytes) -> void* {
        o = (o + 255) & ~(size_t)255;
        void* p = wsp + o;
        o += bytes;
        return p;
    };
    float*  wT       = (float*)alloc(C_ * 9 * sizeof(float));
    int*    pixkey   = (int*)alloc(NPTS * sizeof(int));
    int4*   ofs4     = (int4*)alloc(NPTS * sizeof(int4));
    float*  wxa      = (float*)alloc(NPTS * sizeof(float));
    float*  wya      = (float*)alloc(NPTS * sizeof(float));
    float*  wa       = (float*)alloc(NPTS * sizeof(float));
    float4* wts4     = (float4*)alloc(NPTS * sizeof(float4));
    // contiguous zero region: cnt_pix | cnt_tok | wsum
    int*    cnt_pix  = (int*)alloc((size_t)(B_ * HW_ + NTOK) * sizeof(int)
                                   + (size_t)NTOK * sizeof(float));
    int*    cnt_tok  = cnt_pix + B_ * HW_;
    float*  wsum     = (float*)(cnt_tok + NTOK);
    int*    off_pix  = (int*)alloc((size_t)(B_ * HW_ + 1) * sizeof(int));
    int*    off_tok  = (int*)alloc((size_t)(NTOK + 1) * sizeof(int));
    int*    cur_pix  = (int*)alloc((size_t)(B_ * HW_) * sizeof(int));
    int*    cur_tok  = (int*)alloc((size_t)NTOK * sizeof(int));
    int*    list_pix = (int*)alloc(NPTS * sizeof(int));
    int*    list_tok = (int*)alloc(NPTS * sizeof(int));

    // ---- adaptive channel chunk so fmap+convout fit in ws_size ----
    size_t small_end = (o + 255) & ~(size_t)255;
    size_t perchan = (size_t)B_ * HW_ * 2 * sizeof(float);
    size_t avail = (ws_size > small_end + 1024) ? ws_size - small_end - 1024 : 0;
    int cc = 8;
    const int ladder[6] = {384, 256, 128, 64, 32, 16};
    for (int k = 0; k < 6; ++k)
        if (avail >= (size_t)ladder[k] * perchan) { cc = ladder[k]; break; }

    float* fmap    = (float*)alloc((size_t)B_ * HW_ * cc * sizeof(float));
    float* convout = (float*)alloc((size_t)B_ * HW_ * cc * sizeof(float));

    hipMemsetAsync(cnt_pix, 0,
                   (size_t)(B_ * HW_ + NTOK) * sizeof(int) + (size_t)NTOK * sizeof(float),
                   stream);

    k_wT<<<(C_ * 9 + 255) / 256, 256, 0, stream>>>(conv_w, wT);
    k_points<<<NPTS / 256, 256, 0, stream>>>(loc_orig, idx_agg, agg_w,
                                             pixkey, ofs4, wxa, wya, wa,
                                             cnt_pix, cnt_tok, wsum);
    k_scan<<<1, 1024, 0, stream>>>(cnt_pix, B_ * HW_, off_pix, cur_pix);
    k_scan<<<1, 1024, 0, stream>>>(cnt_tok, NTOK, off_tok, cur_tok);
    k_fill<<<NPTS / 256, 256, 0, stream>>>(pixkey, idx_agg, wxa, wya, wa, wsum,
                                           cur_pix, cur_tok, list_pix, list_tok, wts4);

    const float4* x4 = (const float4*)x;
    switch (cc) {
        case 384: run_chunks<384>(x4, off_pix, list_pix, off_tok, list_tok, ofs4, wts4,
                                  wT, conv_b, fmap, convout, out, stream); break;
        case 256: run_chunks<256>(x4, off_pix, list_pix, off_tok, list_tok, ofs4, wts4,
                                  wT, conv_b, fmap, convout, out, stream); break;
        case 128: run_chunks<128>(x4, off_pix, list_pix, off_tok, list_tok, ofs4, wts4,
                                  wT, conv_b, fmap, convout, out, stream); break;
        case  64: run_chunks< 64>(x4, off_pix, list_pix, off_tok, list_tok, ofs4, wts4,
                                  wT, conv_b, fmap, convout, out, stream); break;
        case  32: run_chunks< 32>(x4, off_pix, list_pix, off_tok, list_tok, ofs4, wts4,
                                  wT, conv_b, fmap, convout, out, stream); break;
        case  16: run_chunks< 16>(x4, off_pix, list_pix, off_tok, list_tok, ofs4, wts4,
                                  wT, conv_b, fmap, convout, out, stream); break;
        default:  run_chunks<  8>(x4, off_pix, list_pix, off_tok, list_tok, ofs4, wts4,
                                  wT, conv_b, fmap, convout, out, stream); break;
    }
}

// Round 6
// 345.062 us; speedup vs baseline: 2.3416x; 1.4837x over previous
//
#include <hip/hip_runtime.h>

// Problem constants (fixed by setup_inputs in the reference; fp32 world confirmed R4)
#define B_    16
#define N_    1536
#define C_    768
#define N0_   3072
#define H_    64
#define W_    48
#define HW_   (H_ * W_)        // 3072
#define NPTS  (B_ * N0_)       // 49152
#define NTOK  (B_ * N_)        // 24576
#define NPIX  (B_ * HW_)       // 49152
#define NSCAN (NPIX + NTOK)    // 73728 = 288 * 256
#define NBP   (NPIX / 256)     // 192
#define NBALL (NSCAN / 256)    // 288
#define EPS_  1e-6f
#define TY_   4                // conv tile rows per block
#define TX_   8                // conv tile cols per block

// ---------------- transpose conv weights to [9][C] for coalesced conv reads ----
__global__ void k_wT(const float* __restrict__ w, float* __restrict__ wT) {
    int i = blockIdx.x * blockDim.x + threadIdx.x;   // over C_*9
    if (i < C_ * 9) { int c = i / 9, k = i - c * 9; wT[k * C_ + c] = w[i]; }
}

// ---------------- per-point precompute + histograms + wsum ----------------
__global__ void k_points(const float* __restrict__ loc_orig,
                         const int* __restrict__ idx_agg,
                         const float* __restrict__ agg_w,
                         int* __restrict__ pixkey, int4* __restrict__ ofs4,
                         float* __restrict__ wxa, float* __restrict__ wya,
                         float* __restrict__ wa,
                         int* __restrict__ cnt_pix, int* __restrict__ cnt_tok,
                         float* __restrict__ wsum) {
    int i = blockIdx.x * blockDim.x + threadIdx.x;
    if (i >= NPTS) return;
    int b = i / N0_;
    float lx = loc_orig[2 * (size_t)i];
    float ly = loc_orig[2 * (size_t)i + 1];
    lx = fminf(fmaxf(lx, -1.f), 1.f);
    ly = fminf(fmaxf(ly, -1.f), 1.f);
    float px = 0.5f * (lx + 1.f) * (float)W_ - 0.5f;   // matches np ref exactly
    float py = 0.5f * (ly + 1.f) * (float)H_ - 0.5f;
    // nearest pixel (round-half-even == np.round)
    int ixn = min(max((int)rintf(px), 0), W_ - 1);
    int iyn = min(max((int)rintf(py), 0), H_ - 1);
    int pk = b * HW_ + iyn * W_ + ixn;
    pixkey[i] = pk;
    // bilinear corners (clipped), weights per reference (may be negative at edges)
    int x0 = min(max((int)floorf(px), 0), W_ - 1);
    int x1 = min(x0 + 1, W_ - 1);
    int y0 = min(max((int)floorf(py), 0), H_ - 1);
    int y1 = min(y0 + 1, H_ - 1);
    wxa[i] = fminf((float)x1, px) - (float)x0;
    wya[i] = fminf((float)y1, py) - (float)y0;
    ofs4[i] = make_int4(y0 * W_ + x0, y0 * W_ + x1, y1 * W_ + x0, y1 * W_ + x1);
    float w = agg_w[i];
    wa[i] = w;
    atomicAdd(&cnt_pix[pk], 1);
    int tk = b * N_ + idx_agg[i];
    atomicAdd(&cnt_tok[tk], 1);
    atomicAdd(&wsum[tk], w);
}

// ---------------- hierarchical scan over contiguous cnt_pix|cnt_tok -----------
// A: per-block exclusive scan + block sums
__global__ __launch_bounds__(256)
void k_scanA(const int* __restrict__ cnt, int* __restrict__ pre, int* __restrict__ bsum) {
    __shared__ int sh[256];
    int b = blockIdx.x, t = threadIdx.x;
    int i = b * 256 + t;
    int v = cnt[i];
    sh[t] = v;
    __syncthreads();
    for (int d = 1; d < 256; d <<= 1) {
        int x = sh[t];
        int y = (t >= d) ? sh[t - d] : 0;
        __syncthreads();
        sh[t] = x + y;
        __syncthreads();
    }
    pre[i] = sh[t] - v;            // exclusive within block
    if (t == 255) bsum[b] = sh[255];
}

// B: segmented scan of the 288 block sums (segment boundary at block NBP)
__global__ __launch_bounds__(256)
void k_scanB(const int* __restrict__ bsum, int* __restrict__ bbase,
             int* __restrict__ off_pix, int* __restrict__ off_tok) {
    __shared__ int sh[256];
    int t = threadIdx.x;
    // segment 1: pix block sums [0, NBP)
    int v = (t < NBP) ? bsum[t] : 0;
    sh[t] = v;
    __syncthreads();
    for (int d = 1; d < 256; d <<= 1) {
        int x = sh[t];
        int y = (t >= d) ? sh[t - d] : 0;
        __syncthreads();
        sh[t] = x + y;
        __syncthreads();
    }
    if (t < NBP) bbase[t] = sh[t] - v;
    __syncthreads();
    // segment 2: tok block sums [NBP, NBALL)
    int nbt = NBALL - NBP;
    v = (t < nbt) ? bsum[NBP + t] : 0;
    sh[t] = v;
    __syncthreads();
    for (int d = 1; d < 256; d <<= 1) {
        int x = sh[t];
        int y = (t >= d) ? sh[t - d] : 0;
        __syncthreads();
        sh[t] = x + y;
        __syncthreads();
    }
    if (t < nbt) bbase[NBP + t] = sh[t] - v;
    if (t == 0) { off_pix[NPIX] = NPTS; off_tok[NTOK] = NPTS; }
}

// C: add block bases, write off/cur
__global__ __launch_bounds__(256)
void k_scanC(const int* __restrict__ pre, const int* __restrict__ bbase,
             int* __restrict__ off_pix, int* __restrict__ cur_pix,
             int* __restrict__ off_tok, int* __restrict__ cur_tok) {
    int b = blockIdx.x, t = threadIdx.x;
    int i = b * 256 + t;
    int val = pre[i] + bbase[b];
    if (b < NBP) { off_pix[i] = val; cur_pix[i] = val; }
    else { int j = i - NPIX; off_tok[j] = val; cur_tok[j] = val; }
}

// ---------------- CSR fill + precompute premultiplied bilinear weights ----------
__global__ void k_fill(const int* __restrict__ pixkey, const int* __restrict__ idx_agg,
                       const float* __restrict__ wxa, const float* __restrict__ wya,
                       const float* __restrict__ wa, const float* __restrict__ wsum,
                       int* __restrict__ cur_pix, int* __restrict__ cur_tok,
                       int* __restrict__ list_pix, int* __restrict__ list_tok,
                       float4* __restrict__ wts4) {
    int i = blockIdx.x * blockDim.x + threadIdx.x;
    if (i >= NPTS) return;
    int b = i / N0_;
    int tok = idx_agg[i];
    int tk = b * N_ + tok;
    int s1 = atomicAdd(&cur_pix[pixkey[i]], 1);
    list_pix[s1] = tk;                 // direct x-row index for scatter
    int s2 = atomicAdd(&cur_tok[tk], 1);
    list_tok[s2] = i;
    float wn = wa[i] / (wsum[tk] + EPS_);    // ref: w / (segsum + eps)
    float wx = wxa[i], wy = wya[i];
    wts4[i] = make_float4((1.f - wx) * (1.f - wy) * wn, wx * (1.f - wy) * wn,
                          (1.f - wx) * wy * wn,         wx * wy * wn);
}

// ---------------- token2map: per-pixel float4 gather, normalized write --------
template<int CC>
__global__ __launch_bounds__(CC / 4)
void k_scatter(const float4* __restrict__ x4, const int* __restrict__ off_pix,
               const int* __restrict__ list_pix, float4* __restrict__ fmap4,
               int cbase4) {
    int pk = blockIdx.x;              // [0, B*HW)
    int t = threadIdx.x;              // [0, CC/4)
    int s = off_pix[pk], e = off_pix[pk + 1];
    float4 a = make_float4(0.f, 0.f, 0.f, 0.f);
    for (int j = s; j < e; ++j) {
        int row = list_pix[j];        // b*N + tok
        float4 v = x4[(size_t)row * (C_ / 4) + cbase4 + t];
        a.x += v.x; a.y += v.y; a.z += v.z; a.w += v.w;
    }
    float sc = 1.f / ((float)(e - s) + EPS_);
    a.x *= sc; a.y *= sc; a.z *= sc; a.w *= sc;
    fmap4[(size_t)pk * (CC / 4) + t] = a;
}

// ---------------- depthwise 3x3, register-tiled TYxTX pixels per thread -------
template<int CC>
__global__ __launch_bounds__(CC)
void k_conv(const float* __restrict__ fmap, const float* __restrict__ wT,
            const float* __restrict__ cb, float* __restrict__ out, int cbase) {
    int tile = blockIdx.x;                        // (W/TX)*(H/TY) tiles
    int tx0 = (tile % (W_ / TX_)) * TX_;
    int ty0 = (tile / (W_ / TX_)) * TY_;
    int b = blockIdx.y;
    int c = threadIdx.x;                          // < CC
    const float* base = fmap + (size_t)b * HW_ * CC + c;
    float v[TY_ + 2][TX_ + 2];
#pragma unroll
    for (int r = 0; r < TY_ + 2; ++r) {
        int yy = ty0 + r - 1;
        bool yok = (unsigned)yy < (unsigned)H_;
#pragma unroll
        for (int j = 0; j < TX_ + 2; ++j) {
            int xx = tx0 + j - 1;
            bool ok = yok && ((unsigned)xx < (unsigned)W_);   // block-uniform predicate
            v[r][j] = ok ? base[(size_t)(yy * W_ + xx) * CC] : 0.f;
        }
    }
    int cg = cbase + c;
    float k0 = wT[0 * C_ + cg], k1 = wT[1 * C_ + cg], k2 = wT[2 * C_ + cg];
    float k3 = wT[3 * C_ + cg], k4 = wT[4 * C_ + cg], k5 = wT[5 * C_ + cg];
    float k6 = wT[6 * C_ + cg], k7 = wT[7 * C_ + cg], k8 = wT[8 * C_ + cg];
    float bias = cb[cg];
    float* ob = out + (size_t)b * HW_ * CC + c;
#pragma unroll
    for (int r = 0; r < TY_; ++r) {
#pragma unroll
        for (int j = 0; j < TX_; ++j) {
            float acc = bias
                + k0 * v[r][j]     + k1 * v[r][j + 1]     + k2 * v[r][j + 2]
                + k3 * v[r + 1][j] + k4 * v[r + 1][j + 1] + k5 * v[r + 1][j + 2]
                + k6 * v[r + 2][j] + k7 * v[r + 2][j + 1] + k8 * v[r + 2][j + 2];
            ob[(size_t)((ty0 + r) * W_ + tx0 + j) * CC] = acc;
        }
    }
}

// ---------------- map2token: per-token float4 gather with precomputed wts -----
template<int CC>
__global__ __launch_bounds__(CC / 4)
void k_gather(const float4* __restrict__ conv4, const int* __restrict__ off_tok,
              const int* __restrict__ list_tok, const int4* __restrict__ ofs4,
              const float4* __restrict__ wts4, float4* __restrict__ out4,
              int cbase4) {
    int tk = blockIdx.x;              // [0, B*N)
    int t = threadIdx.x;              // [0, CC/4)
    int b = tk / N_;
    int s = off_tok[tk], e = off_tok[tk + 1];
    const float4* bb = conv4 + (size_t)b * HW_ * (CC / 4) + t;
    float4 a = make_float4(0.f, 0.f, 0.f, 0.f);
    for (int j = s; j < e; ++j) {
        int i = list_tok[j];
        int4 o = ofs4[i];             // uniform 16B load
        float4 w = wts4[i];           // uniform 16B load (already *wn)
        float4 p0 = bb[(size_t)o.x * (CC / 4)];
        float4 p1 = bb[(size_t)o.y * (CC / 4)];
        float4 p2 = bb[(size_t)o.z * (CC / 4)];
        float4 p3 = bb[(size_t)o.w * (CC / 4)];
        a.x += w.x * p0.x + w.y * p1.x + w.z * p2.x + w.w * p3.x;
        a.y += w.x * p0.y + w.y * p1.y + w.z * p2.y + w.w * p3.y;
        a.z += w.x * p0.z + w.y * p1.z + w.z * p2.z + w.w * p3.z;
        a.w += w.x * p0.w + w.y * p1.w + w.z * p2.w + w.w * p3.w;
    }
    out4[(size_t)tk * (C_ / 4) + cbase4 + t] = a;
}

// ---------------- templated chunk-loop driver ----------------
template<int CC>
static void run_chunks(const float4* x4, const int* off_pix, const int* list_pix,
                       const int* off_tok, const int* list_tok,
                       const int4* ofs4, const float4* wts4,
                       const float* wT, const float* cb,
                       float* fmap, float* convout, float* out,
                       hipStream_t stream) {
    constexpr int NCH = C_ / CC;
    for (int chunk = 0; chunk < NCH; ++chunk) {
        int cbase = chunk * CC;
        k_scatter<CC><<<B_ * HW_, CC / 4, 0, stream>>>(
            x4, off_pix, list_pix, (float4*)fmap, cbase / 4);
        dim3 gconv((W_ / TX_) * (H_ / TY_), B_);
        k_conv<CC><<<gconv, CC, 0, stream>>>(fmap, wT, cb, convout, cbase);
        k_gather<CC><<<NTOK, CC / 4, 0, stream>>>(
            (const float4*)convout, off_tok, list_tok, ofs4, wts4,
            (float4*)out, cbase / 4);
    }
}

extern "C" void kernel_launch(void* const* d_in, const int* in_sizes, int n_in,
                              void* d_out, int out_size, void* d_ws, size_t ws_size,
                              hipStream_t stream) {
    const float* x        = (const float*)d_in[0];
    // d_in[1] = loc (unused by reference)
    const float* loc_orig = (const float*)d_in[2];
    const int*   idx_agg  = (const int*)d_in[3];
    const float* agg_w    = (const float*)d_in[4];
    // d_in[5]=H (64), d_in[6]=W (48) fixed
    const float* conv_w   = (const float*)d_in[7];
    const float* conv_b   = (const float*)d_in[8];
    float* out = (float*)d_out;

    char* wsp = (char*)d_ws;
    size_t o = 0;
    auto alloc = [&](size_t bytes) -> void* {
        o = (o + 255) & ~(size_t)255;
        void* p = wsp + o;
        o += bytes;
        return p;
    };
    float*  wT       = (float*)alloc(C_ * 9 * sizeof(float));
    int*    pixkey   = (int*)alloc(NPTS * sizeof(int));
    int4*   ofs4     = (int4*)alloc(NPTS * sizeof(int4));
    float*  wxa      = (float*)alloc(NPTS * sizeof(float));
    float*  wya      = (float*)alloc(NPTS * sizeof(float));
    float*  wa       = (float*)alloc(NPTS * sizeof(float));
    float4* wts4     = (float4*)alloc(NPTS * sizeof(float4));
    // contiguous zero region: cnt_pix | cnt_tok | wsum
    int*    cnt_pix  = (int*)alloc((size_t)NSCAN * sizeof(int)
                                   + (size_t)NTOK * sizeof(float));
    int*    cnt_tok  = cnt_pix + NPIX;
    float*  wsum     = (float*)(cnt_tok + NTOK);
    int*    pre      = (int*)alloc((size_t)NSCAN * sizeof(int));
    int*    bsum     = (int*)alloc(NBALL * sizeof(int));
    int*    bbase    = (int*)alloc(NBALL * sizeof(int));
    int*    off_pix  = (int*)alloc((size_t)(NPIX + 1) * sizeof(int));
    int*    off_tok  = (int*)alloc((size_t)(NTOK + 1) * sizeof(int));
    int*    cur_pix  = (int*)alloc((size_t)NPIX * sizeof(int));
    int*    cur_tok  = (int*)alloc((size_t)NTOK * sizeof(int));
    int*    list_pix = (int*)alloc(NPTS * sizeof(int));
    int*    list_tok = (int*)alloc(NPTS * sizeof(int));

    // ---- adaptive channel chunk so fmap+convout fit in ws_size ----
    size_t small_end = (o + 255) & ~(size_t)255;
    size_t perchan = (size_t)B_ * HW_ * 2 * sizeof(float);
    size_t avail = (ws_size > small_end + 1024) ? ws_size - small_end - 1024 : 0;
    int cc = 8;
    const int ladder[6] = {384, 256, 128, 64, 32, 16};
    for (int k = 0; k < 6; ++k)
        if (avail >= (size_t)ladder[k] * perchan) { cc = ladder[k]; break; }

    float* fmap    = (float*)alloc((size_t)B_ * HW_ * cc * sizeof(float));
    float* convout = (float*)alloc((size_t)B_ * HW_ * cc * sizeof(float));

    hipMemsetAsync(cnt_pix, 0,
                   (size_t)NSCAN * sizeof(int) + (size_t)NTOK * sizeof(float),
                   stream);

    k_wT<<<(C_ * 9 + 255) / 256, 256, 0, stream>>>(conv_w, wT);
    k_points<<<NPTS / 256, 256, 0, stream>>>(loc_orig, idx_agg, agg_w,
                                             pixkey, ofs4, wxa, wya, wa,
                                             cnt_pix, cnt_tok, wsum);
    k_scanA<<<NBALL, 256, 0, stream>>>(cnt_pix, pre, bsum);
    k_scanB<<<1, 256, 0, stream>>>(bsum, bbase, off_pix, off_tok);
    k_scanC<<<NBALL, 256, 0, stream>>>(pre, bbase, off_pix, cur_pix, off_tok, cur_tok);
    k_fill<<<NPTS / 256, 256, 0, stream>>>(pixkey, idx_agg, wxa, wya, wa, wsum,
                                           cur_pix, cur_tok, list_pix, list_tok, wts4);

    const float4* x4 = (const float4*)x;
    switch (cc) {
        case 384: run_chunks<384>(x4, off_pix, list_pix, off_tok, list_tok, ofs4, wts4,
                                  wT, conv_b, fmap, convout, out, stream); break;
        case 256: run_chunks<256>(x4, off_pix, list_pix, off_tok, list_tok, ofs4, wts4,
                                  wT, conv_b, fmap, convout, out, stream); break;
        case 128: run_chunks<128>(x4, off_pix, list_pix, off_tok, list_tok, ofs4, wts4,
                                  wT, conv_b, fmap, convout, out, stream); break;
        case  64: run_chunks< 64>(x4, off_pix, list_pix, off_tok, list_tok, ofs4, wts4,
                                  wT, conv_b, fmap, convout, out, stream); break;
        case  32: run_chunks< 32>(x4, off_pix, list_pix, off_tok, list_tok, ofs4, wts4,
                                  wT, conv_b, fmap, convout, out, stream); break;
        case  16: run_chunks< 16>(x4, off_pix, list_pix, off_tok, list_tok, ofs4, wts4,
                                  wT, conv_b, fmap, convout, out, stream); break;
        default:  run_chunks<  8>(x4, off_pix, list_pix, off_tok, list_tok, ofs4, wts4,
                                  wT, conv_b, fmap, convout, out, stream); break;
    }
}